// Round 12
// baseline (4280.690 us; speedup 1.0000x reference)
//
#include <hip/hip_runtime.h>
#include <cstddef>

// Problem constants
#define Bb 128
#define Tt 512
#define Ii 256
#define Hh 512
#define G4c 2048      // 4*H
#define BHc (Bb * Hh) // elements in one h buffer

typedef float    f32x4 __attribute__((ext_vector_type(4)));
typedef _Float16 f16x8 __attribute__((ext_vector_type(8)));
typedef unsigned int u32x2 __attribute__((ext_vector_type(2)));
typedef unsigned int u32x4 __attribute__((ext_vector_type(4)));

// ws layout (bytes) — MUST stay under 8 MiB (r9's >8MiB layout hung: ws overrun)
#define OFF_WT1 0u
#define OFF_WT2 3145728u          // 32jb*24ks*4g*64ln*8i*2B
#define OFF_BC1 7340032u          // +32jb*32ks*4g*64ln*8i*2B
#define OFF_BC2 7348224u
#define OFF_H1  7356416u          // 4 slots * 128*512*2 = 524288
#define OFF_H2  7880704u          // 2 slots * 128*512*2 = 262144
#define OFF_FLG 8142848u          // 4 lines * 128B: [(rh<<1)|layer][32 words]
#define OFF_PRG 8143360u          // 4 lines * 128B: [(rh<<1)|layer]
#define OFF_END 8143872u

__device__ __forceinline__ float sigm(float x)  { return 1.0f / (1.0f + __expf(-x)); }
__device__ __forceinline__ float tanhf_(float x){ return 1.0f - 2.0f / (1.0f + __expf(2.0f * x)); }

// ---- coherent (cross-XCD) memory ops: bypass non-coherent L2 via sc0 sc1 ----
__device__ __forceinline__ void ld_g_f16x8_sc(f16x8& dst, const _Float16* p) {
  asm volatile("global_load_dwordx4 %0, %1, off sc0 sc1"
               : "=v"(dst) : "v"(p) : "memory");
}
__device__ __forceinline__ void ld_g_f32x4(f32x4& dst, const float* p) {
  asm volatile("global_load_dwordx4 %0, %1, off" : "=v"(dst) : "v"(p) : "memory");
}
__device__ __forceinline__ void st_g_u32x2_sc(void* p, u32x2 v) {
  asm volatile("global_store_dwordx2 %0, %1, off sc0 sc1" :: "v"(p), "v"(v) : "memory");
}
__device__ __forceinline__ void wait_vm0() {
  asm volatile("s_waitcnt vmcnt(0)" ::: "memory");
}
__device__ __forceinline__ unsigned packh(float a, float b) {
  unsigned short ua = __builtin_bit_cast(unsigned short, (_Float16)a);
  unsigned short ub = __builtin_bit_cast(unsigned short, (_Float16)b);
  return (unsigned)ua | ((unsigned)ub << 16);
}

// Wait: lanes 0-31 read own-layer compact flag line (ONE coalesced 128B
// transaction) vs tl; lanes 32-63 read the single peer progress word vs tp.
__device__ __forceinline__ void pollstep(unsigned* ownline, unsigned* peer, int tid,
                                         unsigned tl, unsigned tp) {
  if (tid < 64) {
    const unsigned tgt = (tid < 32) ? tl : tp;
    const unsigned* p = (tid < 32) ? ownline + tid : peer;
    unsigned v;
    do {
      v = __hip_atomic_load(p, __ATOMIC_RELAXED, __HIP_MEMORY_SCOPE_AGENT);
    } while (__any(v < tgt));
  }
  __syncthreads();
}

// Publish: drain own sc stores (per-wave), block-sync, set own flag word.
__device__ __forceinline__ void publish(unsigned* myword, int tid, unsigned val) {
  wait_vm0();
  __syncthreads();
  if (tid == 0)
    __hip_atomic_store(myword, val, __ATOMIC_RELAXED, __HIP_MEMORY_SCOPE_AGENT);
}

// Pack weights FRAGMENT-MAJOR (round-5/7/10 proven): WtF[jb][ks][g][lane][i] =
//   W_cat[k = ks*32 + (lane>>4)*8 + i][gcol = g*512 + jb*16 + (lane&15)]
__global__ void init_weights(const float* __restrict__ Wx1, const float* __restrict__ Wh1,
                             const float* __restrict__ bx1, const float* __restrict__ bh1,
                             const float* __restrict__ Wx2, const float* __restrict__ Wh2,
                             const float* __restrict__ bx2, const float* __restrict__ bh2,
                             _Float16* __restrict__ Wt1, _Float16* __restrict__ Wt2,
                             float* __restrict__ bc1, float* __restrict__ bc2) {
  const int b = blockIdx.x;
  const int layer = b >> 11;
  const int jb = (b >> 6) & 31;
  const int ln = b & 63;
  const int t  = threadIdx.x;
  const int ks = t >> 3;
  const int i  = t & 7;
  const int k  = (ks << 5) + ((ln >> 4) << 3) + i;
  if (layer == 0) {
    if (ln == 0 && t < 16) {
      #pragma unroll
      for (int g = 0; g < 4; ++g) {
        const int gc = (g << 9) + (jb << 4) + t;
        bc1[gc] = bx1[gc] + bh1[gc];
      }
    }
    if (ks < 24) {
      #pragma unroll
      for (int g = 0; g < 4; ++g) {
        const int gc = (g << 9) + (jb << 4) + (ln & 15);
        const float v = (k < Ii) ? Wx1[k * G4c + gc] : Wh1[(k - Ii) * G4c + gc];
        Wt1[((((size_t)jb * 24 + ks) * 4 + g) * 64 + ln) * 8 + i] = (_Float16)v;
      }
    }
  } else {
    if (ln == 0 && t < 16) {
      #pragma unroll
      for (int g = 0; g < 4; ++g) {
        const int gc = (g << 9) + (jb << 4) + t;
        bc2[gc] = bx2[gc] + bh2[gc];
      }
    }
    #pragma unroll
    for (int g = 0; g < 4; ++g) {
      const int gc = (g << 9) + (jb << 4) + (ln & 15);
      const float v = (k < Hh) ? Wx2[k * G4c + gc] : Wh2[(k - Hh) * G4c + gc];
      Wt2[((((size_t)jb * 32 + ks) * 4 + g) * 64 + ln) * 8 + i] = (_Float16)v;
    }
  }
}

__global__ void zero_ws(u32x4* p, int n) {
  const int i = blockIdx.x * blockDim.x + threadIdx.x;
  if (i < n) p[i] = (u32x4){0u, 0u, 0u, 0u};
}

// Persistent cooperative kernel (round-10 protocol + compact flag line +
// LDS gate-exchange with packed 8B h-stores; gxs gate stride = 256 floats).
// 128 blocks: bid>>6 = layer; blkL = bid&63; jb = blkL>>1; rh = blkL&1.
// Flag word [g4][jb] = e+1 after finishing epoch e (g4 = (rh<<1)|layer).
// prg[g4] = e published by jb0 after its local poll at e.
// L1@e waits [L1 words>=e && prgL2>=e-2] (h1 ring depth 4);
// L2@e waits [L2 words>=e && prgL1>=e]. L1 epilogue publishes prgL1=512.
__global__ __launch_bounds__(256, 1) void lstm_main(
    const float* __restrict__ x,
    const _Float16* __restrict__ Wt1, const _Float16* __restrict__ Wt2,
    const float* __restrict__ bc1, const float* __restrict__ bc2,
    _Float16* h1buf, _Float16* h2buf, unsigned* flags, unsigned* prg,
    const float* __restrict__ Whead, const float* __restrict__ bhead,
    float* __restrict__ out)
{
  extern __shared__ char smem[];
  __shared__ f32x4 gxs[1024];   // 16 KB gate exchange: float idx (wv*4+g)*256 + c15*16 + kg*4 + r

  const int tid  = threadIdx.x;
  const int lane = tid & 63;
  const int wv   = tid >> 6;
  const int bid  = blockIdx.x;
  const int layer = bid >> 6;
  const int blkL  = bid & 63;
  const int jb = blkL >> 1;
  const int rh = blkL & 1;
  const int j0 = jb << 4;
  const int g4 = (rh << 1) | layer;

  unsigned* ownline = flags + (size_t)g4 * 32;
  unsigned* myword  = ownline + jb;
  unsigned* ownp    = prg + (size_t)g4 * 32;
  unsigned* peer    = prg + (size_t)((rh << 1) | (1 - layer)) * 32;

  // ---- stage fragment-major weight slice into LDS (flat copy) ----
  {
    const int elems16 = layer ? (131072 / 16) : (98304 / 16);
    const u32x4* src = (const u32x4*)((layer ? Wt2 : Wt1)
                                      + (size_t)jb * (layer ? 65536 : 49152));
    u32x4* dst = (u32x4*)smem;
    for (int i = tid; i < elems16; i += 256) dst[i] = src[i];
  }
  __syncthreads();

  const int c15 = lane & 15;
  const int kg  = lane >> 4;
  const int arow = (rh << 6) + (wv << 4) + c15;   // batch row for A frags

  // elementwise role: thread owns (row rr, col-quad qq) -> one 8B h store
  const int rr = tid >> 2;          // 0..63 row within block
  const int qq = tid & 3;           // col quad: cols qq*4..+3 of the 16
  const int wv_r = rr >> 4, kg_r = (rr >> 2) & 3, r_r = rr & 3;
  const float* bcL = layer ? bc2 : bc1;
  f32x4 bi0 = *(const f32x4*)(bcL +        j0 + (qq << 2));
  f32x4 bi1 = *(const f32x4*)(bcL +  512 + j0 + (qq << 2));
  f32x4 bi2 = *(const f32x4*)(bcL + 1024 + j0 + (qq << 2));
  f32x4 bi3 = *(const f32x4*)(bcL + 1536 + j0 + (qq << 2));
  const size_t eoff = (size_t)((rh << 6) + rr) * Hh + j0 + (qq << 2);

  const int lb = lane << 4;

  f32x4 cst = {0.f, 0.f, 0.f, 0.f};  // c-state for (row rr, cols qq*4..+3)

  for (int e = 0; e <= Tt; ++e) {
    if (layer == 0) {
      if (e >= Tt) break;   // layer1 done (word 512 set at e=511)
      // 1. x prefetch BEFORE the wait (barrier-independent, plain cached)
      f32x4 xf[16];
      const float* xp = x + (size_t)arow * (Tt * Ii) + (size_t)e * Ii + (kg << 3);
      #pragma unroll
      for (int ks = 0; ks < 8; ++ks) {
        ld_g_f32x4(xf[2*ks],   xp + (ks << 5));
        ld_g_f32x4(xf[2*ks+1], xp + (ks << 5) + 4);
      }
      // 2. wait for producers (1 coalesced line + 1 peer word)
      pollstep(ownline, peer, tid, (unsigned)e, (e >= 2) ? (unsigned)(e - 2) : 0u);
      if (jb == 0 && tid == 0)
        __hip_atomic_store(ownp, (unsigned)e, __ATOMIC_RELAXED, __HIP_MEMORY_SCOPE_AGENT);
      // 3. h1(e-1) loads (sc0 sc1: memory-side coherent)
      f16x8 af[24];
      const _Float16* hp = h1buf + (size_t)((e - 1) & 3) * BHc + arow * Hh + (kg << 3);
      #pragma unroll
      for (int ks = 0; ks < 16; ++ks)
        ld_g_f16x8_sc(af[8 + ks], hp + (ks << 5));
      wait_vm0();
      __builtin_amdgcn_sched_barrier(0);
      #pragma unroll
      for (int ks = 0; ks < 8; ++ks) {
        f16x8 v;
        v[0] = (_Float16)xf[2*ks][0]; v[1] = (_Float16)xf[2*ks][1];
        v[2] = (_Float16)xf[2*ks][2]; v[3] = (_Float16)xf[2*ks][3];
        v[4] = (_Float16)xf[2*ks+1][0]; v[5] = (_Float16)xf[2*ks+1][1];
        v[6] = (_Float16)xf[2*ks+1][2]; v[7] = (_Float16)xf[2*ks+1][3];
        af[ks] = v;
      }
      f32x4 acc0 = {0.f,0.f,0.f,0.f}, acc1 = {0.f,0.f,0.f,0.f};
      f32x4 acc2 = {0.f,0.f,0.f,0.f}, acc3 = {0.f,0.f,0.f,0.f};
      #pragma unroll
      for (int ks = 0; ks < 24; ++ks) {
        const char* bp = smem + (ks << 12) + lb;
        acc0 = __builtin_amdgcn_mfma_f32_16x16x32_f16(af[ks], *(const f16x8*)(bp       ), acc0, 0, 0, 0);
        acc1 = __builtin_amdgcn_mfma_f32_16x16x32_f16(af[ks], *(const f16x8*)(bp + 1024), acc1, 0, 0, 0);
        acc2 = __builtin_amdgcn_mfma_f32_16x16x32_f16(af[ks], *(const f16x8*)(bp + 2048), acc2, 0, 0, 0);
        acc3 = __builtin_amdgcn_mfma_f32_16x16x32_f16(af[ks], *(const f16x8*)(bp + 3072), acc3, 0, 0, 0);
      }
      // gate exchange -> packed h store
      gxs[((wv*4 + 0)*16 + c15)*4 + kg] = acc0;
      gxs[((wv*4 + 1)*16 + c15)*4 + kg] = acc1;
      gxs[((wv*4 + 2)*16 + c15)*4 + kg] = acc2;
      gxs[((wv*4 + 3)*16 + c15)*4 + kg] = acc3;
      __syncthreads();
      const float* gb = (const float*)gxs;
      float hv[4];
      #pragma unroll
      for (int cc = 0; cc < 4; ++cc) {
        const int fi = (wv_r*4)*256 + ((qq<<2) + cc)*16 + (kg_r<<2) + r_r;  // gate 0
        const float iv = sigm (gb[fi      ] + bi0[cc]);
        const float fv = sigm (gb[fi + 256] + bi1[cc]);
        const float gv = tanhf_(gb[fi + 512] + bi2[cc]);
        const float ov = sigm (gb[fi + 768] + bi3[cc]);
        const float cv = fv * cst[cc] + iv * gv;
        cst[cc] = cv;
        hv[cc] = ov * tanhf_(cv);
      }
      u32x2 pk = { packh(hv[0], hv[1]), packh(hv[2], hv[3]) };
      st_g_u32x2_sc((char*)(h1buf + (size_t)(e & 3) * BHc + eoff), pk);
      publish(myword, tid, (unsigned)(e + 1));
    } else {
      if (e == 0) {
        publish(myword, tid, 1u);
      } else {
        pollstep(ownline, peer, tid, (unsigned)e, (unsigned)e);
        if (jb == 0 && tid == 0)
          __hip_atomic_store(ownp, (unsigned)e, __ATOMIC_RELAXED, __HIP_MEMORY_SCOPE_AGENT);
        f16x8 af[32];
        const _Float16* h1p = h1buf + (size_t)((e - 1) & 3) * BHc + arow * Hh + (kg << 3);
        const _Float16* h2p = h2buf + (size_t)(e & 1) * BHc + arow * Hh + (kg << 3);
        #pragma unroll
        for (int ks = 0; ks < 16; ++ks)
          ld_g_f16x8_sc(af[ks], h1p + (ks << 5));
        #pragma unroll
        for (int ks = 0; ks < 16; ++ks)
          ld_g_f16x8_sc(af[16 + ks], h2p + (ks << 5));
        wait_vm0();
        __builtin_amdgcn_sched_barrier(0);
        f32x4 acc0 = {0.f,0.f,0.f,0.f}, acc1 = {0.f,0.f,0.f,0.f};
        f32x4 acc2 = {0.f,0.f,0.f,0.f}, acc3 = {0.f,0.f,0.f,0.f};
        #pragma unroll
        for (int ks = 0; ks < 32; ++ks) {
          const char* bp = smem + (ks << 12) + lb;
          acc0 = __builtin_amdgcn_mfma_f32_16x16x32_f16(af[ks], *(const f16x8*)(bp       ), acc0, 0, 0, 0);
          acc1 = __builtin_amdgcn_mfma_f32_16x16x32_f16(af[ks], *(const f16x8*)(bp + 1024), acc1, 0, 0, 0);
          acc2 = __builtin_amdgcn_mfma_f32_16x16x32_f16(af[ks], *(const f16x8*)(bp + 2048), acc2, 0, 0, 0);
          acc3 = __builtin_amdgcn_mfma_f32_16x16x32_f16(af[ks], *(const f16x8*)(bp + 3072), acc3, 0, 0, 0);
        }
        gxs[((wv*4 + 0)*16 + c15)*4 + kg] = acc0;
        gxs[((wv*4 + 1)*16 + c15)*4 + kg] = acc1;
        gxs[((wv*4 + 2)*16 + c15)*4 + kg] = acc2;
        gxs[((wv*4 + 3)*16 + c15)*4 + kg] = acc3;
        __syncthreads();
        const float* gb = (const float*)gxs;
        float hv[4];
        #pragma unroll
        for (int cc = 0; cc < 4; ++cc) {
          const int fi = (wv_r*4)*256 + ((qq<<2) + cc)*16 + (kg_r<<2) + r_r;
          const float iv = sigm (gb[fi      ] + bi0[cc]);
          const float fv = sigm (gb[fi + 256] + bi1[cc]);
          const float gv = tanhf_(gb[fi + 512] + bi2[cc]);
          const float ov = sigm (gb[fi + 768] + bi3[cc]);
          const float cv = fv * cst[cc] + iv * gv;
          cst[cc] = cv;
          hv[cc] = ov * tanhf_(cv);
        }
        u32x2 pk = { packh(hv[0], hv[1]), packh(hv[2], hv[3]) };
        st_g_u32x2_sc((char*)(h2buf + (size_t)((e + 1) & 1) * BHc + eoff), pk);
        publish(myword, tid, (unsigned)(e + 1));
      }
    }
  }

  // epilogues
  if (layer == 0) {
    if (jb == 0) {
      pollstep(ownline, peer, tid, (unsigned)Tt, 0u);
      if (tid == 0)
        __hip_atomic_store(ownp, (unsigned)Tt, __ATOMIC_RELAXED, __HIP_MEMORY_SCOPE_AGENT);
    }
  } else if (jb == 0) {
    // head: out[b][c] = h2_T[b,:] . W_head[:,c] + b_head[c]; h2_T = h2buf slot 1
    pollstep(ownline, peer, tid, (unsigned)(Tt + 1), 0u);
    const int b_ = (rh << 6) + (tid >> 2);
    const int cc = tid & 3;
    const _Float16* hr = h2buf + BHc + (size_t)b_ * Hh;
    float s = bhead[cc];
    #pragma unroll
    for (int half = 0; half < 2; ++half) {
      f16x8 hv[32];
      #pragma unroll
      for (int kk = 0; kk < 32; ++kk)
        ld_g_f16x8_sc(hv[kk], hr + (half << 8) + (kk << 3));
      wait_vm0();
      #pragma unroll
      for (int kk = 0; kk < 32; ++kk) {
        const int k = (half << 8) + (kk << 3);
        #pragma unroll
        for (int j = 0; j < 8; ++j)
          s += (float)hv[kk][j] * Whead[(k + j) * 4 + cc];
      }
    }
    out[b_ * 4 + cc] = s;
  }
}

extern "C" void kernel_launch(void* const* d_in, const int* in_sizes, int n_in,
                              void* d_out, int out_size, void* d_ws, size_t ws_size,
                              hipStream_t stream) {
  const float* x   = (const float*)d_in[0];
  const float* Wx1 = (const float*)d_in[1];
  const float* bx1 = (const float*)d_in[2];
  const float* Wh1 = (const float*)d_in[3];
  const float* bh1 = (const float*)d_in[4];
  const float* Wx2 = (const float*)d_in[5];
  const float* bx2 = (const float*)d_in[6];
  const float* Wh2 = (const float*)d_in[7];
  const float* bh2 = (const float*)d_in[8];
  const float* Whd = (const float*)d_in[9];
  const float* bhd = (const float*)d_in[10];

  char* ws = (char*)d_ws;
  _Float16* Wt1 = (_Float16*)(ws + OFF_WT1);
  _Float16* Wt2 = (_Float16*)(ws + OFF_WT2);
  float* bc1 = (float*)(ws + OFF_BC1);
  float* bc2 = (float*)(ws + OFF_BC2);
  _Float16* h1b = (_Float16*)(ws + OFF_H1);
  _Float16* h2b = (_Float16*)(ws + OFF_H2);
  unsigned* flg = (unsigned*)(ws + OFF_FLG);
  unsigned* prg = (unsigned*)(ws + OFF_PRG);
  float* out = (float*)d_out;

  init_weights<<<4096, 256, 0, stream>>>(Wx1, Wh1, bx1, bh1, Wx2, Wh2, bx2, bh2,
                                         Wt1, Wt2, bc1, bc2);
  {
    u32x4* zp = (u32x4*)(ws + OFF_H1);
    const int n = (int)((OFF_END - OFF_H1) / 16);  // zero h buffers + flags + prg
    zero_ws<<<(n + 255) / 256, 256, 0, stream>>>(zp, n);
  }
  (void)hipFuncSetAttribute((const void*)lstm_main,
                            hipFuncAttributeMaxDynamicSharedMemorySize, 131072);
  void* args[] = {(void*)&x, (void*)&Wt1, (void*)&Wt2, (void*)&bc1, (void*)&bc2,
                  (void*)&h1b, (void*)&h2b, (void*)&flg, (void*)&prg,
                  (void*)&Whd, (void*)&bhd, (void*)&out};
  (void)hipLaunchCooperativeKernel((const void*)lstm_main, dim3(128), dim3(256),
                                   args, 131072, stream);
}

// Round 15
// 4216.607 us; speedup vs baseline: 1.0152x; 1.0152x over previous
//
#include <hip/hip_runtime.h>
#include <cstddef>

// Problem constants
#define Bb 128
#define Tt 512
#define Ii 256
#define Hh 512
#define G4c 2048      // 4*H
#define BHc (Bb * Hh) // elements in one h buffer
#define FSTRIDE 32    // u32s per flag (128B line each)

typedef float    f32x4 __attribute__((ext_vector_type(4)));
typedef _Float16 f16x8 __attribute__((ext_vector_type(8)));
typedef unsigned int u32x4 __attribute__((ext_vector_type(4)));

// ws layout (bytes) — END <= 8159744 (proven-safe bound)
#define OFF_WT1 0u
#define OFF_WT2 3145728u          // 32jb*24ks*4g*64ln*8i*2B
#define OFF_BC1 7340032u          // +32jb*32ks*4g*64ln*8i*2B
#define OFF_BC2 7348224u
#define OFF_H1  7356416u          // 4 slots * 128*512*2 = 524288
#define OFF_H2  7880704u          // 2 slots * 128*512*2 = 262144
#define OFF_FLG 8142848u          // 128 flags * 128B  [rh*64 + layer*32 + jb]
#define OFF_PRG 8159232u          // 4 prog lines * 128B [(rh<<1)|layer]
#define OFF_END 8159744u

__device__ __forceinline__ float sigm(float x)  { return 1.0f / (1.0f + __expf(-x)); }
__device__ __forceinline__ float tanhf_(float x){ return 1.0f - 2.0f / (1.0f + __expf(2.0f * x)); }

// ---- coherent (cross-XCD) memory ops: bypass non-coherent L2 via sc0 sc1 ----
__device__ __forceinline__ void ld_g_f16x8_sc(f16x8& dst, const _Float16* p) {
  asm volatile("global_load_dwordx4 %0, %1, off sc0 sc1"
               : "=v"(dst) : "v"(p) : "memory");
}
__device__ __forceinline__ void ld_g_f32x4(f32x4& dst, const float* p) {
  asm volatile("global_load_dwordx4 %0, %1, off" : "=v"(dst) : "v"(p) : "memory");
}
__device__ __forceinline__ void st_g_f16_sc(_Float16* p, _Float16 v) {
  unsigned u = (unsigned)__builtin_bit_cast(unsigned short, v);
  asm volatile("global_store_short %0, %1, off sc0 sc1" :: "v"(p), "v"(u) : "memory");
}
__device__ __forceinline__ void wait_vm0() {
  asm volatile("s_waitcnt vmcnt(0)" ::: "memory");
}

// Poll 16 padded member flags [0..15] of base16 (lanes 0-15 of wave 0).
__device__ __forceinline__ void poll_half(unsigned* base16, int tid, unsigned tgt) {
  if (tid < 64) {
    unsigned v = 0xffffffffu;
    do {
      if (tid < 16)
        v = __hip_atomic_load(base16 + (size_t)tid * FSTRIDE,
                              __ATOMIC_RELAXED, __HIP_MEMORY_SCOPE_AGENT);
    } while (__any(v < tgt));
  }
  __syncthreads();
}

// Poll the single peer progress word (lane 0, broadcast-friendly).
__device__ __forceinline__ void poll_peer(unsigned* peer, int tid, unsigned tgt) {
  if (tid < 64) {
    unsigned v = 0xffffffffu;
    do {
      if (tid == 0)
        v = __hip_atomic_load(peer, __ATOMIC_RELAXED, __HIP_MEMORY_SCOPE_AGENT);
    } while (__any(v < tgt));
  }
  __syncthreads();
}

// Full own-line + peer poll (epilogues only; r10-proven).
__device__ __forceinline__ void pollstep(unsigned* grpL, unsigned* peer, int tid,
                                         unsigned tl, unsigned tp) {
  if (tid < 64) {
    const unsigned tgt = (tid < 32) ? tl : tp;
    const unsigned* p = (tid < 32) ? grpL + (size_t)tid * FSTRIDE : peer;
    unsigned v;
    do {
      v = __hip_atomic_load(p, __ATOMIC_RELAXED, __HIP_MEMORY_SCOPE_AGENT);
    } while (__any(v < tgt));
  }
  __syncthreads();
}

// Publish: drain own sc stores (per-wave), block-sync, set own flag.
__device__ __forceinline__ void publish(unsigned* myflag, int tid, unsigned val) {
  wait_vm0();
  __syncthreads();
  if (tid == 0)
    __hip_atomic_store(myflag, val, __ATOMIC_RELAXED, __HIP_MEMORY_SCOPE_AGENT);
}

// Pack weights FRAGMENT-MAJOR (rounds 5/7/10 proven): WtF[jb][ks][g][lane][i] =
//   W_cat[k = ks*32 + (lane>>4)*8 + i][gcol = g*512 + jb*16 + (lane&15)]
__global__ void init_weights(const float* __restrict__ Wx1, const float* __restrict__ Wh1,
                             const float* __restrict__ bx1, const float* __restrict__ bh1,
                             const float* __restrict__ Wx2, const float* __restrict__ Wh2,
                             const float* __restrict__ bx2, const float* __restrict__ bh2,
                             _Float16* __restrict__ Wt1, _Float16* __restrict__ Wt2,
                             float* __restrict__ bc1, float* __restrict__ bc2) {
  const int b = blockIdx.x;
  const int layer = b >> 11;
  const int jb = (b >> 6) & 31;
  const int ln = b & 63;
  const int t  = threadIdx.x;
  const int ks = t >> 3;
  const int i  = t & 7;
  const int k  = (ks << 5) + ((ln >> 4) << 3) + i;
  if (layer == 0) {
    if (ln == 0 && t < 16) {
      #pragma unroll
      for (int g = 0; g < 4; ++g) {
        const int gc = (g << 9) + (jb << 4) + t;
        bc1[gc] = bx1[gc] + bh1[gc];
      }
    }
    if (ks < 24) {
      #pragma unroll
      for (int g = 0; g < 4; ++g) {
        const int gc = (g << 9) + (jb << 4) + (ln & 15);
        const float v = (k < Ii) ? Wx1[k * G4c + gc] : Wh1[(k - Ii) * G4c + gc];
        Wt1[((((size_t)jb * 24 + ks) * 4 + g) * 64 + ln) * 8 + i] = (_Float16)v;
      }
    }
  } else {
    if (ln == 0 && t < 16) {
      #pragma unroll
      for (int g = 0; g < 4; ++g) {
        const int gc = (g << 9) + (jb << 4) + t;
        bc2[gc] = bx2[gc] + bh2[gc];
      }
    }
    #pragma unroll
    for (int g = 0; g < 4; ++g) {
      const int gc = (g << 9) + (jb << 4) + (ln & 15);
      const float v = (k < Hh) ? Wx2[k * G4c + gc] : Wh2[(k - Hh) * G4c + gc];
      Wt2[((((size_t)jb * 32 + ks) * 4 + g) * 64 + ln) * 8 + i] = (_Float16)v;
    }
  }
}

__global__ void zero_ws(u32x4* p, int n) {
  const int i = blockIdx.x * blockDim.x + threadIdx.x;
  if (i < n) p[i] = (u32x4){0u, 0u, 0u, 0u};
}

// Persistent cooperative kernel (r10 protocol; waits pipelined with loads).
// 128 blocks: bid>>6 = layer; blkL = bid&63; jb = blkL>>1; rh = blkL&1.
// Flags [g4][jb] = e+1 after finishing epoch e (g4 = (rh<<1)|layer), padded lines.
// prg[g4] = e published once both own-half polls at e pass (== all own flags >= e).
// L1@e: poll-lo(e) -> h1-lo loads -> poll-hi(e) -> h1-hi loads -> MFMA ->
//       elementwise -> poll prgL2>=e-2 (anti-overwrite, gates stores only) -> store.
// L2@e: poll-lo(e) -> h2-lo -> poll-hi(e) -> h2-hi -> poll prgL1>=e -> h1 -> MFMA.
__global__ __launch_bounds__(256, 1) void lstm_main(
    const float* __restrict__ x,
    const _Float16* __restrict__ Wt1, const _Float16* __restrict__ Wt2,
    const float* __restrict__ bc1, const float* __restrict__ bc2,
    _Float16* h1buf, _Float16* h2buf, unsigned* flags, unsigned* prg,
    const float* __restrict__ Whead, const float* __restrict__ bhead,
    float* __restrict__ out)
{
  extern __shared__ char smem[];

  const int tid  = threadIdx.x;
  const int lane = tid & 63;
  const int wv   = tid >> 6;
  const int bid  = blockIdx.x;
  const int layer = bid >> 6;
  const int blkL  = bid & 63;
  const int jb = blkL >> 1;
  const int rh = blkL & 1;
  const int j0 = jb << 4;

  unsigned* grpL   = flags + (size_t)((rh << 6) + (layer << 5)) * FSTRIDE;
  unsigned* grpH   = grpL + (size_t)16 * FSTRIDE;
  unsigned* myflag = grpL + (size_t)jb * FSTRIDE;
  unsigned* ownp   = prg + (size_t)((rh << 1) | layer) * FSTRIDE;
  unsigned* peer   = prg + (size_t)((rh << 1) | (1 - layer)) * FSTRIDE;

  // ---- stage fragment-major weight slice into LDS (flat copy) ----
  {
    const int elems16 = layer ? (131072 / 16) : (98304 / 16);
    const u32x4* src = (const u32x4*)((layer ? Wt2 : Wt1)
                                      + (size_t)jb * (layer ? 65536 : 49152));
    u32x4* dst = (u32x4*)smem;
    for (int i = tid; i < elems16; i += 256) dst[i] = src[i];
  }
  __syncthreads();

  const int c15 = lane & 15;
  const int kg  = lane >> 4;
  const int arow  = (rh << 6) + (wv << 4) + c15;
  const int wrow0 = (rh << 6) + (wv << 4) + (kg << 2);

  const float* bc = layer ? bc2 : bc1;
  const float bias0 = bc[        j0 + c15];
  const float bias1 = bc[ 512 +  j0 + c15];
  const float bias2 = bc[1024 +  j0 + c15];
  const float bias3 = bc[1536 +  j0 + c15];

  const int lb = lane << 4;

  f32x4 cst = {0.f, 0.f, 0.f, 0.f};

  for (int e = 0; e <= Tt; ++e) {
    if (layer == 0) {
      if (e >= Tt) break;   // layer1 done (flag 512 set at e=511)
      // 1. x prefetch (barrier-independent, plain cached)
      f32x4 xf[16];
      const float* xp = x + (size_t)arow * (Tt * Ii) + (size_t)e * Ii + (kg << 3);
      #pragma unroll
      for (int ks = 0; ks < 8; ++ks) {
        ld_g_f32x4(xf[2*ks],   xp + (ks << 5));
        ld_g_f32x4(xf[2*ks+1], xp + (ks << 5) + 4);
      }
      f16x8 af[24];
      const _Float16* hp = h1buf + (size_t)((e - 1) & 3) * BHc + arow * Hh + (kg << 3);
      // 2. lo producers ready -> issue h1-lo (k 0..255)
      poll_half(grpL, tid, (unsigned)e);
      #pragma unroll
      for (int ks = 0; ks < 8; ++ks)
        ld_g_f16x8_sc(af[8 + ks], hp + (ks << 5));
      // 3. hi producers ready (overlaps lo load latency) -> issue h1-hi
      poll_half(grpH, tid, (unsigned)e);
      #pragma unroll
      for (int ks = 8; ks < 16; ++ks)
        ld_g_f16x8_sc(af[8 + ks], hp + (ks << 5));
      // full own line confirmed -> aggregated progress
      if (jb == 0 && tid == 0)
        __hip_atomic_store(ownp, (unsigned)e, __ATOMIC_RELAXED, __HIP_MEMORY_SCOPE_AGENT);
      wait_vm0();
      __builtin_amdgcn_sched_barrier(0);
      #pragma unroll
      for (int ks = 0; ks < 8; ++ks) {
        f16x8 v;
        v[0] = (_Float16)xf[2*ks][0]; v[1] = (_Float16)xf[2*ks][1];
        v[2] = (_Float16)xf[2*ks][2]; v[3] = (_Float16)xf[2*ks][3];
        v[4] = (_Float16)xf[2*ks+1][0]; v[5] = (_Float16)xf[2*ks+1][1];
        v[6] = (_Float16)xf[2*ks+1][2]; v[7] = (_Float16)xf[2*ks+1][3];
        af[ks] = v;
      }
      f32x4 acc0 = {0.f,0.f,0.f,0.f}, acc1 = {0.f,0.f,0.f,0.f};
      f32x4 acc2 = {0.f,0.f,0.f,0.f}, acc3 = {0.f,0.f,0.f,0.f};
      #pragma unroll
      for (int ks = 0; ks < 24; ++ks) {
        const char* bp = smem + (ks << 12) + lb;
        acc0 = __builtin_amdgcn_mfma_f32_16x16x32_f16(af[ks], *(const f16x8*)(bp       ), acc0, 0, 0, 0);
        acc1 = __builtin_amdgcn_mfma_f32_16x16x32_f16(af[ks], *(const f16x8*)(bp + 1024), acc1, 0, 0, 0);
        acc2 = __builtin_amdgcn_mfma_f32_16x16x32_f16(af[ks], *(const f16x8*)(bp + 2048), acc2, 0, 0, 0);
        acc3 = __builtin_amdgcn_mfma_f32_16x16x32_f16(af[ks], *(const f16x8*)(bp + 3072), acc3, 0, 0, 0);
      }
      float hout[4];
      #pragma unroll
      for (int r = 0; r < 4; ++r) {
        const float iv = sigm(acc0[r] + bias0);
        const float fv = sigm(acc1[r] + bias1);
        const float gv = tanhf_(acc2[r] + bias2);
        const float ov = sigm(acc3[r] + bias3);
        const float cv = fv * cst[r] + iv * gv;
        cst[r] = cv;
        hout[r] = ov * tanhf_(cv);
      }
      // 4. anti-overwrite gate (only stores depend on it): prgL2 >= e-2
      poll_peer(peer, tid, (e >= 2) ? (unsigned)(e - 2) : 0u);
      _Float16* hw = h1buf + (size_t)(e & 3) * BHc;
      #pragma unroll
      for (int r = 0; r < 4; ++r)
        st_g_f16_sc(hw + (size_t)(wrow0 + r) * Hh + j0 + c15, (_Float16)hout[r]);
      publish(myflag, tid, (unsigned)(e + 1));
    } else {
      if (e == 0) {
        publish(myflag, tid, 1u);
      } else {
        f16x8 af[32];
        const _Float16* h2p = h2buf + (size_t)(e & 1) * BHc + arow * Hh + (kg << 3);
        const _Float16* h1p = h1buf + (size_t)((e - 1) & 3) * BHc + arow * Hh + (kg << 3);
        // 1. own lo producers -> h2-lo (k 0..255)
        poll_half(grpL, tid, (unsigned)e);
        #pragma unroll
        for (int ks = 0; ks < 8; ++ks)
          ld_g_f16x8_sc(af[16 + ks], h2p + (ks << 5));
        // 2. own hi producers (overlaps h2-lo latency) -> h2-hi
        poll_half(grpH, tid, (unsigned)e);
        #pragma unroll
        for (int ks = 8; ks < 16; ++ks)
          ld_g_f16x8_sc(af[16 + ks], h2p + (ks << 5));
        if (jb == 0 && tid == 0)
          __hip_atomic_store(ownp, (unsigned)e, __ATOMIC_RELAXED, __HIP_MEMORY_SCOPE_AGENT);
        // 3. peer gate (overlaps h2 load latency) -> h1 loads
        poll_peer(peer, tid, (unsigned)e);
        #pragma unroll
        for (int ks = 0; ks < 16; ++ks)
          ld_g_f16x8_sc(af[ks], h1p + (ks << 5));
        wait_vm0();
        __builtin_amdgcn_sched_barrier(0);
        f32x4 acc0 = {0.f,0.f,0.f,0.f}, acc1 = {0.f,0.f,0.f,0.f};
        f32x4 acc2 = {0.f,0.f,0.f,0.f}, acc3 = {0.f,0.f,0.f,0.f};
        #pragma unroll
        for (int ks = 0; ks < 32; ++ks) {
          const char* bp = smem + (ks << 12) + lb;
          acc0 = __builtin_amdgcn_mfma_f32_16x16x32_f16(af[ks], *(const f16x8*)(bp       ), acc0, 0, 0, 0);
          acc1 = __builtin_amdgcn_mfma_f32_16x16x32_f16(af[ks], *(const f16x8*)(bp + 1024), acc1, 0, 0, 0);
          acc2 = __builtin_amdgcn_mfma_f32_16x16x32_f16(af[ks], *(const f16x8*)(bp + 2048), acc2, 0, 0, 0);
          acc3 = __builtin_amdgcn_mfma_f32_16x16x32_f16(af[ks], *(const f16x8*)(bp + 3072), acc3, 0, 0, 0);
        }
        float hout[4];
        #pragma unroll
        for (int r = 0; r < 4; ++r) {
          const float iv = sigm(acc0[r] + bias0);
          const float fv = sigm(acc1[r] + bias1);
          const float gv = tanhf_(acc2[r] + bias2);
          const float ov = sigm(acc3[r] + bias3);
          const float cv = fv * cst[r] + iv * gv;
          cst[r] = cv;
          hout[r] = ov * tanhf_(cv);
        }
        _Float16* hw = h2buf + (size_t)((e + 1) & 1) * BHc;
        #pragma unroll
        for (int r = 0; r < 4; ++r)
          st_g_f16_sc(hw + (size_t)(wrow0 + r) * Hh + j0 + c15, (_Float16)hout[r]);
        publish(myflag, tid, (unsigned)(e + 1));
      }
    }
  }

  // epilogues (r10-proven)
  if (layer == 0) {
    if (jb == 0) {
      pollstep(grpL, peer, tid, (unsigned)Tt, 0u);
      if (tid == 0)
        __hip_atomic_store(ownp, (unsigned)Tt, __ATOMIC_RELAXED, __HIP_MEMORY_SCOPE_AGENT);
    }
  } else if (jb == 0) {
    // head: out[b][c] = h2_T[b,:] . W_head[:,c] + b_head[c]; h2_T = h2buf slot 1
    pollstep(grpL, peer, tid, (unsigned)(Tt + 1), 0u);
    const int b_ = (rh << 6) + (tid >> 2);
    const int cc = tid & 3;
    const _Float16* hr = h2buf + BHc + (size_t)b_ * Hh;
    float s = bhead[cc];
    #pragma unroll
    for (int half = 0; half < 2; ++half) {
      f16x8 hv[32];
      #pragma unroll
      for (int kk = 0; kk < 32; ++kk)
        ld_g_f16x8_sc(hv[kk], hr + (half << 8) + (kk << 3));
      wait_vm0();
      #pragma unroll
      for (int kk = 0; kk < 32; ++kk) {
        const int k = (half << 8) + (kk << 3);
        #pragma unroll
        for (int j = 0; j < 8; ++j)
          s += (float)hv[kk][j] * Whead[(k + j) * 4 + cc];
      }
    }
    out[b_ * 4 + cc] = s;
  }
}

extern "C" void kernel_launch(void* const* d_in, const int* in_sizes, int n_in,
                              void* d_out, int out_size, void* d_ws, size_t ws_size,
                              hipStream_t stream) {
  const float* x   = (const float*)d_in[0];
  const float* Wx1 = (const float*)d_in[1];
  const float* bx1 = (const float*)d_in[2];
  const float* Wh1 = (const float*)d_in[3];
  const float* bh1 = (const float*)d_in[4];
  const float* Wx2 = (const float*)d_in[5];
  const float* bx2 = (const float*)d_in[6];
  const float* Wh2 = (const float*)d_in[7];
  const float* bh2 = (const float*)d_in[8];
  const float* Whd = (const float*)d_in[9];
  const float* bhd = (const float*)d_in[10];

  char* ws = (char*)d_ws;
  _Float16* Wt1 = (_Float16*)(ws + OFF_WT1);
  _Float16* Wt2 = (_Float16*)(ws + OFF_WT2);
  float* bc1 = (float*)(ws + OFF_BC1);
  float* bc2 = (float*)(ws + OFF_BC2);
  _Float16* h1b = (_Float16*)(ws + OFF_H1);
  _Float16* h2b = (_Float16*)(ws + OFF_H2);
  unsigned* flg = (unsigned*)(ws + OFF_FLG);
  unsigned* prg = (unsigned*)(ws + OFF_PRG);
  float* out = (float*)d_out;

  init_weights<<<4096, 256, 0, stream>>>(Wx1, Wh1, bx1, bh1, Wx2, Wh2, bx2, bh2,
                                         Wt1, Wt2, bc1, bc2);
  {
    u32x4* zp = (u32x4*)(ws + OFF_H1);
    const int n = (int)((OFF_END - OFF_H1) / 16);  // zero h buffers + flags + prg
    zero_ws<<<(n + 255) / 256, 256, 0, stream>>>(zp, n);
  }
  (void)hipFuncSetAttribute((const void*)lstm_main,
                            hipFuncAttributeMaxDynamicSharedMemorySize, 131072);
  void* args[] = {(void*)&x, (void*)&Wt1, (void*)&Wt2, (void*)&bc1, (void*)&bc2,
                  (void*)&h1b, (void*)&h2b, (void*)&flg, (void*)&prg,
                  (void*)&Whd, (void*)&bhd, (void*)&out};
  (void)hipLaunchCooperativeKernel((const void*)lstm_main, dim3(128), dim3(256),
                                   args, 131072, stream);
}

// Round 16
// 3559.661 us; speedup vs baseline: 1.2026x; 1.1846x over previous
//
#include <hip/hip_runtime.h>
#include <cstddef>

// Problem constants
#define Tt 512
#define Ii 256
#define Hh 512
#define G4c 2048
#define FSTRIDE 32        // u32 per flag (128B line)
#define SPIN_CAP 50000000

typedef float    f32x4 __attribute__((ext_vector_type(4)));
typedef _Float16 f16x8 __attribute__((ext_vector_type(8)));
typedef unsigned int u32x4 __attribute__((ext_vector_type(4)));

// ws layout (bytes) — END <= 8159744 (proven-safe bound)
#define OFF_WT1 0u
#define OFF_WT2 3145728u          // 32jb*24ks*4g*64ln*8i*2B
#define OFF_BC1 7340032u          // +32jb*32ks*4g*64ln*8i*2B
#define OFF_BC2 7348224u
#define OFF_H1  7356416u          // [4 rh][2 slot][32*512] f16 = 262144
#define OFF_H2  7618560u          // [4 rh][2 slot][32*512] f16 = 262144
#define OFF_FLG 7880704u          // [8 g][32 jb] * 128B = 32768
#define OFF_END 7913472u

#define MFMA(a,b,c) __builtin_amdgcn_mfma_f32_16x16x32_f16((a),(b),(c),0,0,0)

__device__ __forceinline__ float sigm(float x)  { return 1.0f / (1.0f + __expf(-x)); }
__device__ __forceinline__ float tanhf_(float x){ return 1.0f - 2.0f / (1.0f + __expf(2.0f * x)); }

// ---- coherent (cross-XCD) memory ops (green-proven family) ----
__device__ __forceinline__ void ld_g_f16x8_sc(f16x8& dst, const _Float16* p) {
  asm volatile("global_load_dwordx4 %0, %1, off sc0 sc1"
               : "=v"(dst) : "v"(p) : "memory");
}
__device__ __forceinline__ void ld_g_f32x4(f32x4& dst, const float* p) {
  asm volatile("global_load_dwordx4 %0, %1, off" : "=v"(dst) : "v"(p) : "memory");
}
__device__ __forceinline__ void st_g_u32_sc(void* p, unsigned v) {
  asm volatile("global_store_dword %0, %1, off sc0 sc1" :: "v"(p), "v"(v) : "memory");
}
__device__ __forceinline__ void wait_vm0() {
  asm volatile("s_waitcnt vmcnt(0)" ::: "memory");
}
__device__ __forceinline__ unsigned packh(float a, float b) {
  unsigned short ua = __builtin_bit_cast(unsigned short, (_Float16)a);
  unsigned short ub = __builtin_bit_cast(unsigned short, (_Float16)b);
  return (unsigned)ua | ((unsigned)ub << 16);
}

// Direct dual poll (r7-proven fastest): lanes 0-31 watch own-group member
// flags vs tl; lanes 32-63 watch peer-group member flags vs tp. Capped.
__device__ __forceinline__ void pollstep(unsigned* own, unsigned* peer,
                                         int* s_abort, int tid,
                                         unsigned tl, unsigned tp) {
  if (tid < 64) {
    const unsigned tgt = (tid < 32) ? tl : tp;
    const unsigned* p = (tid < 32) ? own + (size_t)tid * FSTRIDE
                                   : peer + (size_t)(tid - 32) * FSTRIDE;
    unsigned v; int guard = 0;
    do {
      v = __hip_atomic_load(p, __ATOMIC_RELAXED, __HIP_MEMORY_SCOPE_AGENT);
      if (++guard > SPIN_CAP) { if (tid == 0) *s_abort = 1; break; }
    } while (__any(v < tgt));
  }
  __syncthreads();
}

// Publish: drain own sc stores (per-wave), block-sync, set own flag.
__device__ __forceinline__ void publish(unsigned* myflag, int tid, unsigned val) {
  wait_vm0();
  __syncthreads();
  if (tid == 0)
    __hip_atomic_store(myflag, val, __ATOMIC_RELAXED, __HIP_MEMORY_SCOPE_AGENT);
}

// Pack weights FRAGMENT-MAJOR (rounds 5/7/10/12 proven): WtF[jb][ks][g][lane][i] =
//   W_cat[k = ks*32 + (lane>>4)*8 + i][gcol = g*512 + jb*16 + (lane&15)]
__global__ void init_weights(const float* __restrict__ Wx1, const float* __restrict__ Wh1,
                             const float* __restrict__ bx1, const float* __restrict__ bh1,
                             const float* __restrict__ Wx2, const float* __restrict__ Wh2,
                             const float* __restrict__ bx2, const float* __restrict__ bh2,
                             _Float16* __restrict__ Wt1, _Float16* __restrict__ Wt2,
                             float* __restrict__ bc1, float* __restrict__ bc2) {
  const int b = blockIdx.x;
  const int layer = b >> 11;
  const int jb = (b >> 6) & 31;
  const int ln = b & 63;
  const int t  = threadIdx.x;
  const int ks = t >> 3;
  const int i  = t & 7;
  const int k  = (ks << 5) + ((ln >> 4) << 3) + i;
  if (layer == 0) {
    if (ln == 0 && t < 16) {
      #pragma unroll
      for (int g = 0; g < 4; ++g) {
        const int gc = (g << 9) + (jb << 4) + t;
        bc1[gc] = bx1[gc] + bh1[gc];
      }
    }
    if (ks < 24) {
      #pragma unroll
      for (int g = 0; g < 4; ++g) {
        const int gc = (g << 9) + (jb << 4) + (ln & 15);
        const float v = (k < Ii) ? Wx1[k * G4c + gc] : Wh1[(k - Ii) * G4c + gc];
        Wt1[((((size_t)jb * 24 + ks) * 4 + g) * 64 + ln) * 8 + i] = (_Float16)v;
      }
    }
  } else {
    if (ln == 0 && t < 16) {
      #pragma unroll
      for (int g = 0; g < 4; ++g) {
        const int gc = (g << 9) + (jb << 4) + t;
        bc2[gc] = bx2[gc] + bh2[gc];
      }
    }
    #pragma unroll
    for (int g = 0; g < 4; ++g) {
      const int gc = (g << 9) + (jb << 4) + (ln & 15);
      const float v = (k < Hh) ? Wx2[k * G4c + gc] : Wh2[(k - Hh) * G4c + gc];
      Wt2[((((size_t)jb * 32 + ks) * 4 + g) * 64 + ln) * 8 + i] = (_Float16)v;
    }
  }
}

__global__ void zero_ws(u32x4* p, int n) {
  const int i = blockIdx.x * blockDim.x + threadIdx.x;
  if (i < n) p[i] = (u32x4){0u, 0u, 0u, 0u};
}

// Persistent cooperative kernel: 256 blocks (1/CU), 8 groups of 32.
// g = bid>>5: layer = g&1, rh = g>>1 (batch rows rh*32..+31); jb = bid&31
// (16 H-cols). Per-block: 4 waves, 32 rows x 16 cols output.
// Flags [g][jb] = t+1 after finishing step t. Direct dual-poll schedule:
//   L1@t: own >= t (h1(t-1) ready) && peer(L2) >= t-1 (slot t&1 free)
//   L2@t: own >= t (h2(t-1) ready) && peer(L1) >= t+1 (h1(t) ready)
// Deadlock-free: t1<=t2 && t2<t1-1 is contradictory.
__global__ __launch_bounds__(256, 1) void lstm_main(
    const float* __restrict__ x,
    const _Float16* __restrict__ Wt1, const _Float16* __restrict__ Wt2,
    const float* __restrict__ bc1, const float* __restrict__ bc2,
    _Float16* h1buf, _Float16* h2buf, unsigned* flags,
    const float* __restrict__ Whead, const float* __restrict__ bhead,
    float* __restrict__ out)
{
  extern __shared__ char smem[];
  __shared__ f32x4 gxs[512];          // 8 KB gate exchange
  __shared__ int s_abort;

  const int tid  = threadIdx.x;
  const int lane = tid & 63;
  const int wv   = tid >> 6;
  const int bid  = blockIdx.x;
  const int g    = bid >> 5;
  const int jb   = bid & 31;
  const int layer = g & 1;
  const int rh    = g >> 1;
  const int j0 = jb << 4;
  if (tid == 0) s_abort = 0;

  unsigned* own  = flags + (size_t)(g << 5) * FSTRIDE;
  unsigned* peer = flags + (size_t)((g ^ 1) << 5) * FSTRIDE;
  unsigned* myfl = own + (size_t)jb * FSTRIDE;

  // ---- stage fragment-major weight slice into LDS (flat copy) ----
  {
    const int elems16 = layer ? (131072 / 16) : (98304 / 16);
    const u32x4* src = (const u32x4*)((layer ? Wt2 : Wt1)
                                      + (size_t)jb * (layer ? 65536 : 49152));
    u32x4* dst = (u32x4*)smem;
    for (int i = tid; i < elems16; i += 256) dst[i] = src[i];
  }
  __syncthreads();

  const int rt  = wv & 1;           // row-tile (16 rows)
  const int u   = wv >> 1;          // gate pair {2u, 2u+1}
  const int c15 = lane & 15;
  const int kg  = lane >> 4;
  const int lb  = lane << 4;

  _Float16* h1b = h1buf + (size_t)rh * 2 * 16384;
  _Float16* h2b = h2buf + (size_t)rh * 2 * 16384;
  const int browA = rh * 32 + rt * 16 + c15;   // global batch row for A frags
  const int arowl = rt * 16 + c15;             // row within group (0..31)

  // elementwise role: (row erow 0..31, col pair col2)
  const int erow = tid >> 3;
  const int col2 = (tid & 7) << 1;
  const int ert = erow >> 4, er15 = erow & 15;
  const float* bcL = layer ? bc2 : bc1;
  float bi_[4][2];
  #pragma unroll
  for (int gg = 0; gg < 4; ++gg) {
    bi_[gg][0] = bcL[(gg << 9) + j0 + col2];
    bi_[gg][1] = bcL[(gg << 9) + j0 + col2 + 1];
  }
  float cst0 = 0.f, cst1 = 0.f;
  const size_t eo = (size_t)erow * 512 + j0 + col2;   // offset in 32x512 buf

  for (int t = 0; t < Tt; ++t) {
    f32x4 a0 = {0.f,0.f,0.f,0.f}, a1 = {0.f,0.f,0.f,0.f};
    if (layer == 0) {
      // x prefetch before the wait (plain cached)
      f32x4 xf[16];
      const float* xp = x + ((size_t)browA * Tt + t) * Ii + (kg << 3);
      #pragma unroll
      for (int ks = 0; ks < 8; ++ks) {
        ld_g_f32x4(xf[2 * ks],     xp + (ks << 5));
        ld_g_f32x4(xf[2 * ks + 1], xp + (ks << 5) + 4);
      }
      pollstep(own, peer, &s_abort, tid,
               (unsigned)t, (t >= 1) ? (unsigned)(t - 1) : 0u);
      if (s_abort) return;
      f16x8 af[24];
      if (t > 0) {
        const _Float16* hp = h1b + (size_t)((t - 1) & 1) * 16384
                             + (size_t)arowl * 512 + (kg << 3);
        #pragma unroll
        for (int ks = 0; ks < 16; ++ks)
          ld_g_f16x8_sc(af[8 + ks], hp + (ks << 5));
      } else {
        #pragma unroll
        for (int ks = 0; ks < 16; ++ks)
          #pragma unroll
          for (int q = 0; q < 8; ++q) af[8 + ks][q] = (_Float16)0.f;
      }
      wait_vm0();
      __builtin_amdgcn_sched_barrier(0);
      #pragma unroll
      for (int ks = 0; ks < 8; ++ks) {
        f16x8 v;
        v[0] = (_Float16)xf[2*ks][0]; v[1] = (_Float16)xf[2*ks][1];
        v[2] = (_Float16)xf[2*ks][2]; v[3] = (_Float16)xf[2*ks][3];
        v[4] = (_Float16)xf[2*ks+1][0]; v[5] = (_Float16)xf[2*ks+1][1];
        v[6] = (_Float16)xf[2*ks+1][2]; v[7] = (_Float16)xf[2*ks+1][3];
        af[ks] = v;
      }
      #pragma unroll
      for (int ks = 0; ks < 24; ++ks) {
        const char* bp = smem + (ks << 12) + (u << 11) + lb;
        a0 = MFMA(af[ks], *(const f16x8*)(bp), a0);
        a1 = MFMA(af[ks], *(const f16x8*)(bp + 1024), a1);
      }
    } else {
      pollstep(own, peer, &s_abort, tid, (unsigned)t, (unsigned)(t + 1));
      if (s_abort) return;
      f16x8 af[32];
      const _Float16* h1p = h1b + (size_t)(t & 1) * 16384
                            + (size_t)arowl * 512 + (kg << 3);
      #pragma unroll
      for (int ks = 0; ks < 16; ++ks)
        ld_g_f16x8_sc(af[ks], h1p + (ks << 5));
      if (t > 0) {
        const _Float16* h2p = h2b + (size_t)((t - 1) & 1) * 16384
                              + (size_t)arowl * 512 + (kg << 3);
        #pragma unroll
        for (int ks = 0; ks < 16; ++ks)
          ld_g_f16x8_sc(af[16 + ks], h2p + (ks << 5));
      } else {
        #pragma unroll
        for (int ks = 0; ks < 16; ++ks)
          #pragma unroll
          for (int q = 0; q < 8; ++q) af[16 + ks][q] = (_Float16)0.f;
      }
      wait_vm0();
      __builtin_amdgcn_sched_barrier(0);
      #pragma unroll
      for (int ks = 0; ks < 32; ++ks) {
        const char* bp = smem + (ks << 12) + (u << 11) + lb;
        a0 = MFMA(af[ks], *(const f16x8*)(bp), a0);
        a1 = MFMA(af[ks], *(const f16x8*)(bp + 1024), a1);
      }
    }

    // gate exchange via LDS: float idx = (rt*4 + gate)*256 + col*16 + (kg*4+r)
    gxs[((rt * 4 + 2 * u)     * 16 + c15) * 4 + kg] = a0;
    gxs[((rt * 4 + 2 * u + 1) * 16 + c15) * 4 + kg] = a1;
    __syncthreads();

    const float* gb = (const float*)gxs;
    const int f0 = (ert * 4) * 256 + col2 * 16 + er15;
    const int f1 = f0 + 16;
    const float i0 = sigm (gb[f0      ] + bi_[0][0]);
    const float fv0= sigm (gb[f0 + 256] + bi_[1][0]);
    const float g0 = tanhf_(gb[f0 + 512] + bi_[2][0]);
    const float o0 = sigm (gb[f0 + 768] + bi_[3][0]);
    const float i1 = sigm (gb[f1      ] + bi_[0][1]);
    const float fv1= sigm (gb[f1 + 256] + bi_[1][1]);
    const float g1 = tanhf_(gb[f1 + 512] + bi_[2][1]);
    const float o1 = sigm (gb[f1 + 768] + bi_[3][1]);
    const float cv0 = fv0 * cst0 + i0 * g0; cst0 = cv0;
    const float cv1 = fv1 * cst1 + i1 * g1; cst1 = cv1;
    const unsigned hu = packh(o0 * tanhf_(cv0), o1 * tanhf_(cv1));

    _Float16* hw = (layer == 0) ? (h1b + (size_t)(t & 1) * 16384)
                                : (h2b + (size_t)(t & 1) * 16384);
    st_g_u32_sc((char*)(hw + eo), hu);
    __syncthreads();                 // gxs reuse guard before next epoch
    publish(myfl, tid, (unsigned)(t + 1));
  }

  // head: L2-group jb0 blocks; h2_T = h2 slot (511&1)=1
  if (layer == 1 && jb == 0) {
    pollstep(own, peer, &s_abort, tid, (unsigned)Tt, 0u);
    if (s_abort) return;
    if (tid < 128) {
      const int row = tid >> 2;
      const int cc = tid & 3;
      const _Float16* hr = h2b + 16384 + (size_t)row * 512;
      float s = bhead[cc];
      #pragma unroll
      for (int half = 0; half < 4; ++half) {
        f16x8 hv[16];
        #pragma unroll
        for (int j = 0; j < 16; ++j)
          ld_g_f16x8_sc(hv[j], hr + (half << 7) + (j << 3));
        wait_vm0();
        #pragma unroll
        for (int j = 0; j < 16; ++j) {
          const int k = (half << 7) + (j << 3);
          #pragma unroll
          for (int e = 0; e < 8; ++e)
            s += (float)hv[j][e] * Whead[(k + e) * 4 + cc];
        }
      }
      out[(rh * 32 + row) * 4 + cc] = s;
    }
  }
}

extern "C" void kernel_launch(void* const* d_in, const int* in_sizes, int n_in,
                              void* d_out, int out_size, void* d_ws, size_t ws_size,
                              hipStream_t stream) {
  const float* x   = (const float*)d_in[0];
  const float* Wx1 = (const float*)d_in[1];
  const float* bx1 = (const float*)d_in[2];
  const float* Wh1 = (const float*)d_in[3];
  const float* bh1 = (const float*)d_in[4];
  const float* Wx2 = (const float*)d_in[5];
  const float* bx2 = (const float*)d_in[6];
  const float* Wh2 = (const float*)d_in[7];
  const float* bh2 = (const float*)d_in[8];
  const float* Whd = (const float*)d_in[9];
  const float* bhd = (const float*)d_in[10];

  char* ws = (char*)d_ws;
  _Float16* Wt1 = (_Float16*)(ws + OFF_WT1);
  _Float16* Wt2 = (_Float16*)(ws + OFF_WT2);
  float* bc1 = (float*)(ws + OFF_BC1);
  float* bc2 = (float*)(ws + OFF_BC2);
  _Float16* h1b = (_Float16*)(ws + OFF_H1);
  _Float16* h2b = (_Float16*)(ws + OFF_H2);
  unsigned* flg = (unsigned*)(ws + OFF_FLG);
  float* out = (float*)d_out;

  init_weights<<<4096, 256, 0, stream>>>(Wx1, Wh1, bx1, bh1, Wx2, Wh2, bx2, bh2,
                                         Wt1, Wt2, bc1, bc2);
  {
    u32x4* zp = (u32x4*)(ws + OFF_H1);
    const int n = (int)((OFF_END - OFF_H1) / 16);  // h rings + flags
    zero_ws<<<(n + 255) / 256, 256, 0, stream>>>(zp, n);
  }
  (void)hipFuncSetAttribute((const void*)lstm_main,
                            hipFuncAttributeMaxDynamicSharedMemorySize, 131072);
  void* args[] = {(void*)&x, (void*)&Wt1, (void*)&Wt2, (void*)&bc1, (void*)&bc2,
                  (void*)&h1b, (void*)&h2b, (void*)&flg,
                  (void*)&Whd, (void*)&bhd, (void*)&out};
  (void)hipLaunchCooperativeKernel((const void*)lstm_main, dim3(256), dim3(256),
                                   args, 131072, stream);
}